// Round 6
// baseline (206.684 us; speedup 1.0000x reference)
//
#include <hip/hip_runtime.h>
#include <hip/hip_bf16.h>
#include <math.h>

// Problem constants (B=2, S=2048, D=1024, H=16, HD=64)
#define B_  2
#define S_  2048
#define D_  1024
#define H_  16
#define HD_ 64
#define M_  (B_*S_)     // 4096 rows (b,s)
#define N3  (3*D_)      // 3072 stacked Q|K|V projection cols
#define K_  D_          // 1024 contraction
#define LOG2E 1.44269504088896340736f

typedef unsigned short u16;
typedef __bf16 bf16x8 __attribute__((ext_vector_type(8)));
typedef float  f32x4  __attribute__((ext_vector_type(4)));
typedef float  f32x16 __attribute__((ext_vector_type(16)));
typedef unsigned short u16x4 __attribute__((ext_vector_type(4)));
typedef unsigned short u16x8 __attribute__((ext_vector_type(8)));
typedef unsigned int   u32x4v __attribute__((ext_vector_type(4)));

typedef const __attribute__((address_space(1))) unsigned int gu32;
typedef __attribute__((address_space(3)))       unsigned int lu32;

// async global->LDS, 16B per lane. LDS dest must be wave-uniform base + lane*16.
__device__ __forceinline__ void gload_lds16(const void* g, void* l) {
  __builtin_amdgcn_global_load_lds((gu32*)g, (lu32*)l, 16, 0, 0);
}

// round-to-nearest-even f32 -> bf16
__device__ __forceinline__ u16 f2bf(float f) {
  unsigned u = __builtin_bit_cast(unsigned, f);
  u += 0x7fffu + ((u >> 16) & 1u);
  return (u16)(u >> 16);
}

// pack 2 f32 -> 2 bf16 in one u32 (RNE), single instruction
__device__ __forceinline__ unsigned pk2(float lo, float hi) {
  unsigned d;
  asm("v_cvt_pk_bf16_f32 %0, %1, %2" : "=v"(d) : "v"(lo), "v"(hi));
  return d;
}

// ---------------- prep: all 4 f32->bf16 conversions in one launch ----------------
__global__ void k_prep(const float* __restrict__ hs, const float* __restrict__ Wq,
                       const float* __restrict__ Wk, const float* __restrict__ Wv,
                       u16* __restrict__ Xb, u16* __restrict__ Wb) {
  const int NX = M_*D_/4, NW = D_*D_/4;
  int i = blockIdx.x * blockDim.x + threadIdx.x;   // [0, NX+3*NW)
  const float4* src; u16* dst; int off;
  if (i < NX)            { src = (const float4*)hs; dst = Xb;           off = i; }
  else if (i < NX+NW)    { src = (const float4*)Wq; dst = Wb;           off = i-NX; }
  else if (i < NX+2*NW)  { src = (const float4*)Wk; dst = Wb + D_*D_;   off = i-NX-NW; }
  else                   { src = (const float4*)Wv; dst = Wb + 2*D_*D_; off = i-NX-2*NW; }
  float4 v = src[off];
  ushort4 o; o.x = f2bf(v.x); o.y = f2bf(v.y); o.z = f2bf(v.z); o.w = f2bf(v.w);
  reinterpret_cast<ushort4*>(dst)[off] = o;
}

// RoPE tables in f64 (65K entries; cheap at this size).
__global__ void k_tables(float* __restrict__ sinT, float* __restrict__ cosT) {
  int gid = blockIdx.x * blockDim.x + threadIdx.x;  // 2048*32
  int s = gid >> 5, j = gid & 31;
  float invf = (float)exp(-(double)j * (log(10000.0) / 32.0));
  float angf = (float)s * invf;           // mimic f32 angle rounding of reference
  double ang = (double)angf;
  sinT[gid] = (float)sin(ang);
  cosT[gid] = (float)cos(ang);
}

// ---------------- projection GEMM with fused bias+RoPE epilogue ----------------
#define BM 128
#define BN 128
#define BK 64

__global__ __launch_bounds__(256) void k_gemm(const u16* __restrict__ A,
                                              const u16* __restrict__ Bm,
                                              const float* __restrict__ bq,
                                              const float* __restrict__ bk,
                                              const float* __restrict__ bv,
                                              const float* __restrict__ sinT,
                                              const float* __restrict__ cosT,
                                              u16* __restrict__ Qo,
                                              u16* __restrict__ Ko,
                                              u16* __restrict__ Vo) {
  __shared__ alignas(16) u16 As[BM*BK];
  __shared__ alignas(16) u16 Bs[BN*BK];
  const int t = threadIdx.x;
  const int l = t & 63, w = t >> 6;
  const int wr = w >> 1, wc = w & 1;
  const int lr = l & 15, lg = l >> 4;
  const int m0 = blockIdx.y * BM, n0 = blockIdx.x * BN;

  f32x4 acc[4][4] = {};

  for (int k0 = 0; k0 < K_; k0 += BK) {
#pragma unroll
    for (int i = 0; i < 4; ++i) {          // A tile: 16KB, 4 x (256 lanes x 16B)
      int chunk = i*256 + t;
      int row = chunk >> 3, kc = chunk & 7;
      gload_lds16(A + (size_t)(m0+row)*K_ + k0 + kc*8, &As[chunk*8]);
    }
#pragma unroll
    for (int i = 0; i < 4; ++i) {          // B tile
      int chunk = i*256 + t;
      int row = chunk >> 3, kc = chunk & 7;
      gload_lds16(Bm + (size_t)(n0+row)*K_ + k0 + kc*8, &Bs[chunk*8]);
    }
    __syncthreads();
#pragma unroll
    for (int ks = 0; ks < 2; ++ks) {
      bf16x8 a[4], b[4];
#pragma unroll
      for (int m = 0; m < 4; ++m)
        a[m] = *reinterpret_cast<const bf16x8*>(&As[(wr*64 + m*16 + lr)*BK + ks*32 + lg*8]);
#pragma unroll
      for (int n = 0; n < 4; ++n)
        b[n] = *reinterpret_cast<const bf16x8*>(&Bs[(wc*64 + n*16 + lr)*BK + ks*32 + lg*8]);
#pragma unroll
      for (int m = 0; m < 4; ++m)
#pragma unroll
        for (int n = 0; n < 4; ++n)
          acc[m][n] = __builtin_amdgcn_mfma_f32_16x16x32_bf16(a[m], b[n], acc[m][n], 0, 0, 0);
    }
    __syncthreads();
  }

  // ---- fused epilogue ----  C/D layout: col = lane&15, row = (lane>>4)*4 + reg
  const int cw0  = n0 + wc*64;             // wave col base (64-aligned)
  const int proj = cw0 >> 10;              // 0=Q 1=K 2=V (wave-uniform)
  const int h    = (cw0 & (D_-1)) >> 6;
  const int b    = m0 >> 11;               // BM=128 divides S=2048
  const int sb_  = (m0 & (S_-1)) + wr*64;

  if (proj < 2) {
    const float* bias = proj ? bk : bq;
    u16* dst = proj ? Ko : Qo;
    // Q pre-scaled by 0.125*log2(e): folds softmax scale AND exp->exp2
    const float qs = proj ? 1.0f : 0.125f * LOG2E;
    float b1[2], b2[2];
#pragma unroll
    for (int n = 0; n < 2; ++n) {
      b1[n] = bias[h*HD_ + n*16 + lr];
      b2[n] = bias[h*HD_ + n*16 + lr + 32];
    }
#pragma unroll
    for (int m = 0; m < 4; ++m)
#pragma unroll
      for (int r = 0; r < 4; ++r) {
        int s = sb_ + m*16 + lg*4 + r;
        size_t orow = ((size_t)(b*H_ + h)*S_ + s)*HD_;
#pragma unroll
        for (int n = 0; n < 2; ++n) {
          int j = n*16 + lr;
          float x1 = acc[m][n][r]   + b1[n];
          float x2 = acc[m][n+2][r] + b2[n];
          float c  = cosT[(s<<5) + j], sn = sinT[(s<<5) + j];
          dst[orow + j]      = f2bf((x1*c - x2*sn) * qs);
          dst[orow + j + 32] = f2bf((x1*sn + x2*c) * qs);
        }
      }
  } else {
    float bb[4];
#pragma unroll
    for (int n = 0; n < 4; ++n) bb[n] = bv[h*HD_ + n*16 + lr];
#pragma unroll
    for (int m = 0; m < 4; ++m)
#pragma unroll
      for (int r = 0; r < 4; ++r) {
        int s = sb_ + m*16 + lg*4 + r;
        size_t orow = ((size_t)(b*H_ + h)*S_ + s)*HD_;
#pragma unroll
        for (int n = 0; n < 4; ++n)
          Vo[orow + n*16 + lr] = f2bf(acc[m][n][r] + bb[n]);
      }
  }
}

// ---------------- V transpose: Vb (B,H,S,HD) -> Vt (B,H,HD,S), bf16 ----------------
// Key axis PERMUTED within each 16-key block (swap bits 2<->3): position p holds
// key (p&3)|((p&4)<<1)|((p&8)>>1). This makes PV's B-frag (32x32x16 MFMA A-native
// key order (r&3)+8*(r>>2)+4*hi) a contiguous ds_read_b128 in k_attn.
__global__ __launch_bounds__(256) void k_vt2(const u16* __restrict__ Vb,
                                             u16* __restrict__ Vt) {
  __shared__ u16 tile[64*68];              // pad 68: 8B-aligned rows, low conflicts
  const int bh = blockIdx.y, s0 = blockIdx.x * 64, t = threadIdx.x;
#pragma unroll
  for (int i = 0; i < 2; ++i) {
    int chunk = i*256 + t;                 // [0,512)
    int sl = chunk >> 3, c8 = chunk & 7;
    u16x8 v = *reinterpret_cast<const u16x8*>(Vb + ((size_t)bh*S_ + s0 + sl)*HD_ + c8*8);
    u16x4 lo = __builtin_shufflevector(v, v, 0, 1, 2, 3);
    u16x4 hi = __builtin_shufflevector(v, v, 4, 5, 6, 7);
    *reinterpret_cast<u16x4*>(&tile[sl*68 + c8*8])     = lo;
    *reinterpret_cast<u16x4*>(&tile[sl*68 + c8*8 + 4]) = hi;
  }
  __syncthreads();
#pragma unroll
  for (int i = 0; i < 2; ++i) {
    int chunk = i*256 + t;
    int hd = chunk >> 3, sb = chunk & 7;
    u16x8 o;
#pragma unroll
    for (int k = 0; k < 8; ++k) {
      int p   = sb*8 + k;
      int key = (p & ~15) | (p & 3) | ((p & 4) << 1) | ((p & 8) >> 1);
      o[k] = tile[key*68 + hd];
    }
    *reinterpret_cast<u16x8*>(Vt + ((size_t)bh*HD_ + hd)*S_ + s0 + sb*8) = o;
  }
}

// ---------------- flash attention: 4 waves x 32 q-rows, 32x32x16 MFMA ----------
// Same per-wave math as round 5 (verified); launch restructured for 2 blocks/CU:
// 256 threads (4 waves, 128 q-rows), 512 blocks. Swapped QK^T (mfma(K,Q)); P in
// registers, packed via v_cvt_pk_bf16_f32 in native order; Vt key-permuted so PV
// B is a plain swizzled ds_read_b128. Fixed-max softmax (bounded scores).
#define QBW 32
#define NWV 4
#define QTT (QBW*NWV)    // 128 q-rows per block
#define KTL 64
#define NTL (S_/KTL)     // 32 kv tiles

__global__ __launch_bounds__(256) void k_attn(const u16* __restrict__ Q,
                                              const u16* __restrict__ K,
                                              const u16* __restrict__ Vt,
                                              float* __restrict__ out) {
  __shared__ alignas(16) u16 Ks[2][KTL*HD_];   // [key][hd], granule-swizzled
  __shared__ alignas(16) u16 Vs[2][HD_*KTL];   // [hd][key-permuted], swizzled
  __shared__ float lsums[NWV][QBW];
  const int t = threadIdx.x, l = t & 63, w = t >> 6;
  const int q32 = l & 31, hi = l >> 5;

  const int bid = blockIdx.x;
  const int work = (bid & 7) * 64 + (bid >> 3);   // XCD-chunked (512 % 8 == 0)
  const int bh = work >> 4;                       // 4 bh per XCD
  const int q0 = (work & 15) * QTT;

  const u16* Qg = Q  + ((size_t)bh*S_ + q0 + w*QBW)*HD_;
  const u16* Kg = K  + (size_t)bh*S_*HD_;
  const u16* Vg = Vt + (size_t)bh*HD_*S_;

  // Q B-frags (col=qrow=q32, k = kt*16 + hi*8 + i), loaded once from global
  bf16x8 qf[4];
#pragma unroll
  for (int kt = 0; kt < 4; ++kt)
    qf[kt] = *reinterpret_cast<const bf16x8*>(Qg + (size_t)q32*HD_ + kt*16 + hi*8);

  f32x16 O0 = {}, O1 = {};
  float lsum = 0.f;

  // staging: thread t loads 2 K granules + 2 V granules per tile (rows r, r+32);
  // source granule pre-swizzled (rule #21): sg1 = sg ^ (row&7), same for row+32.
  const int srow = t >> 3, sg = t & 7;
  const int sg1 = sg ^ (srow & 7);
  const u16* kq = Kg + (size_t)srow*HD_ + sg1*8;
  const u16* vq = Vg + (size_t)srow*S_  + sg1*8;

  gload_lds16(kq,            &Ks[0][t*8]);
  gload_lds16(kq + 32*HD_,   &Ks[0][2048 + t*8]);
  gload_lds16(vq,            &Vs[0][t*8]);
  gload_lds16(vq + 32*S_,    &Vs[0][2048 + t*8]);
  __syncthreads();

  int cur = 0;
  for (int tile = 0; tile < NTL; ++tile) {
    if (tile + 1 < NTL) {
      const u16* kn = kq + (size_t)(tile+1)*KTL*HD_;
      const u16* vn = vq + (tile+1)*KTL;
      gload_lds16(kn,          &Ks[cur^1][t*8]);
      gload_lds16(kn + 32*HD_, &Ks[cur^1][2048 + t*8]);
      gload_lds16(vn,          &Vs[cur^1][t*8]);
      gload_lds16(vn + 32*S_,  &Vs[cur^1][2048 + t*8]);
    }

    // QK^T swapped: d[key][qrow]; A = K rows (key=kb*32+q32), B = Q
    f32x16 d0 = {}, d1 = {};
    __builtin_amdgcn_s_setprio(1);
#pragma unroll
    for (int kt = 0; kt < 4; ++kt) {
      const int gsw = ((kt*2 + hi) ^ (q32 & 7)) * 8;
      bf16x8 k0 = *reinterpret_cast<const bf16x8*>(&Ks[cur][q32*HD_ + gsw]);
      d0 = __builtin_amdgcn_mfma_f32_32x32x16_bf16(k0, qf[kt], d0, 0, 0, 0);
      bf16x8 k1 = *reinterpret_cast<const bf16x8*>(&Ks[cur][(32 + q32)*HD_ + gsw]);
      d1 = __builtin_amdgcn_mfma_f32_32x32x16_bf16(k1, qf[kt], d1, 0, 0, 0);
    }
    __builtin_amdgcn_s_setprio(0);

    // softmax (fixed max, log2 domain) + pack to PV A-frags in native reg order.
    // chunk c element (hi,i) <-> key c*16 + [(i&3)+8*(i>>2)+4*hi], matching Vt's
    // permuted key axis.
    unsigned pw[4][4];
#pragma unroll
    for (int c = 0; c < 4; ++c) {
      float e[8];
#pragma unroll
      for (int i = 0; i < 8; ++i) {
        float sv = (c < 2) ? d0[(c & 1)*8 + i] : d1[(c & 1)*8 + i];
        e[i] = exp2f(sv);
        lsum += e[i];
      }
#pragma unroll
      for (int j = 0; j < 4; ++j) pw[c][j] = pk2(e[2*j], e[2*j+1]);
    }

    // PV: O[qrow][hd] += P * V; B from Vs rows (hd), keys pre-permuted
    __builtin_amdgcn_s_setprio(1);
#pragma unroll
    for (int c = 0; c < 4; ++c) {
      u32x4v pv_ = {pw[c][0], pw[c][1], pw[c][2], pw[c][3]};
      bf16x8 pa = __builtin_bit_cast(bf16x8, pv_);
      const int gv = ((c*2 + hi) ^ (q32 & 7)) * 8;
      bf16x8 v0 = *reinterpret_cast<const bf16x8*>(&Vs[cur][q32*KTL + gv]);
      O0 = __builtin_amdgcn_mfma_f32_32x32x16_bf16(pa, v0, O0, 0, 0, 0);
      bf16x8 v1 = *reinterpret_cast<const bf16x8*>(&Vs[cur][(32 + q32)*KTL + gv]);
      O1 = __builtin_amdgcn_mfma_f32_32x32x16_bf16(pa, v1, O1, 0, 0, 0);
    }
    __builtin_amdgcn_s_setprio(0);

    __syncthreads();   // drains vmcnt (next buf staged) before swap
    cur ^= 1;
  }

  // full row sum: this lane's 32 keys + partner's 32 keys
  lsum += __shfl_xor(lsum, 32);
  if (l < 32) lsums[w][l] = lsum;    // lsums[w][qrow]; same-wave ds ordering

  // epilogue: O layout col=q32 (hd), row(reg r) = (r&3)+8*(r>>2)+4*hi (qrow)
  const int b = bh >> 4, h = bh & 15;
#pragma unroll
  for (int r = 0; r < 16; ++r) {
    int qrow = (r & 3) + 8*(r >> 2) + 4*hi;
    float inv = 1.f / lsums[w][qrow];
    size_t o = (size_t)(b*S_ + q0 + w*QBW + qrow)*D_ + h*HD_;
    out[o + q32]      = O0[r] * inv;
    out[o + 32 + q32] = O1[r] * inv;
  }
}

// ---------------- launch ----------------
extern "C" void kernel_launch(void* const* d_in, const int* in_sizes, int n_in,
                              void* d_out, int out_size, void* d_ws, size_t ws_size,
                              hipStream_t stream) {
  const float* hs = (const float*)d_in[0];
  const float* Wq = (const float*)d_in[1];
  const float* bq = (const float*)d_in[2];
  const float* Wk = (const float*)d_in[3];
  const float* bk = (const float*)d_in[4];
  const float* Wv = (const float*)d_in[5];
  const float* bv = (const float*)d_in[6];
  float* out = (float*)d_out;

  // ws layout (~48.8 MB total)
  char* ws = (char*)d_ws;
  u16*   Xb   = (u16*)  (ws);                 //  8.0 MB  X bf16 (4096x1024)
  u16*   Wb   = (u16*)  (ws + 8388608);       //  6.0 MB  W stacked bf16 (3072x1024)
  u16*   Qb   = (u16*)  (ws + 14680064);      //  8.0 MB  Q bf16 (B,H,S,HD), pre-scaled
  u16*   Kb   = (u16*)  (ws + 23068672);      //  8.0 MB  K bf16 (B,H,S,HD)
  u16*   Vb   = (u16*)  (ws + 31457280);      //  8.0 MB  V bf16 (B,H,S,HD)
  u16*   Vtb  = (u16*)  (ws + 39845888);      //  8.0 MB  V^T bf16 (B,H,HD,S), key-permuted
  float* sinT = (float*)(ws + 48234496);      //  0.25 MB
  float* cosT = (float*)(ws + 48496640);      //  0.25 MB

  k_prep<<<(M_*D_/4 + 3*(D_*D_/4)) / 256, 256, 0, stream>>>(hs, Wq, Wk, Wv, Xb, Wb);
  k_tables<<<256, 256, 0, stream>>>(sinT, cosT);
  k_gemm<<<dim3(N3/BN, M_/BM), 256, 0, stream>>>(Xb, Wb, bq, bk, bv, sinT, cosT, Qb, Kb, Vb);
  k_vt2<<<dim3(S_/64, B_*H_), 256, 0, stream>>>(Vb, Vtb);
  k_attn<<<512, 256, 0, stream>>>(Qb, Kb, Vtb, out);
}

// Round 7
// 205.832 us; speedup vs baseline: 1.0041x; 1.0041x over previous
//
#include <hip/hip_runtime.h>
#include <hip/hip_bf16.h>
#include <math.h>

// Problem constants (B=2, S=2048, D=1024, H=16, HD=64)
#define B_  2
#define S_  2048
#define D_  1024
#define H_  16
#define HD_ 64
#define M_  (B_*S_)     // 4096 rows (b,s)
#define N3  (3*D_)      // 3072 stacked Q|K|V projection cols
#define K_  D_          // 1024 contraction
#define LOG2E 1.44269504088896340736f

typedef unsigned short u16;
typedef __bf16 bf16x8 __attribute__((ext_vector_type(8)));
typedef float  f32x4  __attribute__((ext_vector_type(4)));
typedef float  f32x16 __attribute__((ext_vector_type(16)));
typedef unsigned short u16x4 __attribute__((ext_vector_type(4)));
typedef unsigned short u16x8 __attribute__((ext_vector_type(8)));
typedef unsigned int   u32x4v __attribute__((ext_vector_type(4)));

typedef const __attribute__((address_space(1))) unsigned int gu32;
typedef __attribute__((address_space(3)))       unsigned int lu32;

// async global->LDS, 16B per lane. LDS dest must be wave-uniform base + lane*16.
__device__ __forceinline__ void gload_lds16(const void* g, void* l) {
  __builtin_amdgcn_global_load_lds((gu32*)g, (lu32*)l, 16, 0, 0);
}

// round-to-nearest-even f32 -> bf16
__device__ __forceinline__ u16 f2bf(float f) {
  unsigned u = __builtin_bit_cast(unsigned, f);
  u += 0x7fffu + ((u >> 16) & 1u);
  return (u16)(u >> 16);
}

// pack 2 f32 -> 2 bf16 in one u32 (RNE), single instruction
__device__ __forceinline__ unsigned pk2(float lo, float hi) {
  unsigned d;
  asm("v_cvt_pk_bf16_f32 %0, %1, %2" : "=v"(d) : "v"(lo), "v"(hi));
  return d;
}

// ---------------- prep: all 4 f32->bf16 conversions in one launch ----------------
__global__ void k_prep(const float* __restrict__ hs, const float* __restrict__ Wq,
                       const float* __restrict__ Wk, const float* __restrict__ Wv,
                       u16* __restrict__ Xb, u16* __restrict__ Wb) {
  const int NX = M_*D_/4, NW = D_*D_/4;
  int i = blockIdx.x * blockDim.x + threadIdx.x;   // [0, NX+3*NW)
  const float4* src; u16* dst; int off;
  if (i < NX)            { src = (const float4*)hs; dst = Xb;           off = i; }
  else if (i < NX+NW)    { src = (const float4*)Wq; dst = Wb;           off = i-NX; }
  else if (i < NX+2*NW)  { src = (const float4*)Wk; dst = Wb + D_*D_;   off = i-NX-NW; }
  else                   { src = (const float4*)Wv; dst = Wb + 2*D_*D_; off = i-NX-2*NW; }
  float4 v = src[off];
  ushort4 o; o.x = f2bf(v.x); o.y = f2bf(v.y); o.z = f2bf(v.z); o.w = f2bf(v.w);
  reinterpret_cast<ushort4*>(dst)[off] = o;
}

// RoPE tables in f64 (65K entries; cheap at this size).
__global__ void k_tables(float* __restrict__ sinT, float* __restrict__ cosT) {
  int gid = blockIdx.x * blockDim.x + threadIdx.x;  // 2048*32
  int s = gid >> 5, j = gid & 31;
  float invf = (float)exp(-(double)j * (log(10000.0) / 32.0));
  float angf = (float)s * invf;           // mimic f32 angle rounding of reference
  double ang = (double)angf;
  sinT[gid] = (float)sin(ang);
  cosT[gid] = (float)cos(ang);
}

// ---------------- projection GEMM with fused bias+RoPE epilogue ----------------
#define BM 128
#define BN 128
#define BK 64

__global__ __launch_bounds__(256) void k_gemm(const u16* __restrict__ A,
                                              const u16* __restrict__ Bm,
                                              const float* __restrict__ bq,
                                              const float* __restrict__ bk,
                                              const float* __restrict__ bv,
                                              const float* __restrict__ sinT,
                                              const float* __restrict__ cosT,
                                              u16* __restrict__ Qo,
                                              u16* __restrict__ Ko,
                                              u16* __restrict__ Vo) {
  __shared__ alignas(16) u16 As[BM*BK];
  __shared__ alignas(16) u16 Bs[BN*BK];
  const int t = threadIdx.x;
  const int l = t & 63, w = t >> 6;
  const int wr = w >> 1, wc = w & 1;
  const int lr = l & 15, lg = l >> 4;

  // XCD-chunked block swizzle (768 blocks = 8 XCDs x 96, bijective): each XCD
  // keeps 4 consecutive A row-panels resident in its private L2.
  const int lin = blockIdx.y * (N3/BN) + blockIdx.x;
  const int wk  = (lin & 7) * 96 + (lin >> 3);
  const int m0 = (wk / (N3/BN)) * BM, n0 = (wk % (N3/BN)) * BN;

  f32x4 acc[4][4] = {};

  for (int k0 = 0; k0 < K_; k0 += BK) {
#pragma unroll
    for (int i = 0; i < 4; ++i) {          // A tile: 16KB, 4 x (256 lanes x 16B)
      int chunk = i*256 + t;
      int row = chunk >> 3, kc = chunk & 7;
      gload_lds16(A + (size_t)(m0+row)*K_ + k0 + kc*8, &As[chunk*8]);
    }
#pragma unroll
    for (int i = 0; i < 4; ++i) {          // B tile
      int chunk = i*256 + t;
      int row = chunk >> 3, kc = chunk & 7;
      gload_lds16(Bm + (size_t)(n0+row)*K_ + k0 + kc*8, &Bs[chunk*8]);
    }
    __syncthreads();
#pragma unroll
    for (int ks = 0; ks < 2; ++ks) {
      bf16x8 a[4], b[4];
#pragma unroll
      for (int m = 0; m < 4; ++m)
        a[m] = *reinterpret_cast<const bf16x8*>(&As[(wr*64 + m*16 + lr)*BK + ks*32 + lg*8]);
#pragma unroll
      for (int n = 0; n < 4; ++n)
        b[n] = *reinterpret_cast<const bf16x8*>(&Bs[(wc*64 + n*16 + lr)*BK + ks*32 + lg*8]);
#pragma unroll
      for (int m = 0; m < 4; ++m)
#pragma unroll
        for (int n = 0; n < 4; ++n)
          acc[m][n] = __builtin_amdgcn_mfma_f32_16x16x32_bf16(a[m], b[n], acc[m][n], 0, 0, 0);
    }
    __syncthreads();
  }

  // ---- fused epilogue ----  C/D layout: col = lane&15, row = (lane>>4)*4 + reg
  const int cw0  = n0 + wc*64;             // wave col base (64-aligned)
  const int proj = cw0 >> 10;              // 0=Q 1=K 2=V (wave-uniform)
  const int h    = (cw0 & (D_-1)) >> 6;
  const int b    = m0 >> 11;               // BM=128 divides S=2048
  const int sb_  = (m0 & (S_-1)) + wr*64;

  if (proj < 2) {
    const float* bias = proj ? bk : bq;
    u16* dst = proj ? Ko : Qo;
    // Q pre-scaled by 0.125*log2(e): folds softmax scale AND exp->exp2
    const float qs = proj ? 1.0f : 0.125f * LOG2E;
    float b1[2], b2[2];
#pragma unroll
    for (int n = 0; n < 2; ++n) {
      b1[n] = bias[h*HD_ + n*16 + lr];
      b2[n] = bias[h*HD_ + n*16 + lr + 32];
    }
#pragma unroll
    for (int m = 0; m < 4; ++m)
#pragma unroll
      for (int r = 0; r < 4; ++r) {
        int s = sb_ + m*16 + lg*4 + r;
        size_t orow = ((size_t)(b*H_ + h)*S_ + s)*HD_;
#pragma unroll
        for (int n = 0; n < 2; ++n) {
          int j = n*16 + lr;
          float x1 = acc[m][n][r]   + b1[n];
          float x2 = acc[m][n+2][r] + b2[n];
          float c  = cosT[(s<<5) + j], sn = sinT[(s<<5) + j];
          dst[orow + j]      = f2bf((x1*c - x2*sn) * qs);
          dst[orow + j + 32] = f2bf((x1*sn + x2*c) * qs);
        }
      }
  } else {
    float bb[4];
#pragma unroll
    for (int n = 0; n < 4; ++n) bb[n] = bv[h*HD_ + n*16 + lr];
#pragma unroll
    for (int m = 0; m < 4; ++m)
#pragma unroll
      for (int r = 0; r < 4; ++r) {
        int s = sb_ + m*16 + lg*4 + r;
        size_t orow = ((size_t)(b*H_ + h)*S_ + s)*HD_;
#pragma unroll
        for (int n = 0; n < 4; ++n)
          Vo[orow + n*16 + lr] = f2bf(acc[m][n][r] + bb[n]);
      }
  }
}

// ---------------- V transpose: Vb (B,H,S,HD) -> Vt (B,H,HD,S), bf16 ----------------
// Key axis PERMUTED within each 16-key block (swap bits 2<->3): position p holds
// key (p&3)|((p&4)<<1)|((p&8)>>1). This makes PV's B-frag (32x32x16 MFMA A-native
// key order (r&3)+8*(r>>2)+4*hi) a contiguous ds_read_b128 in k_attn.
__global__ __launch_bounds__(256) void k_vt2(const u16* __restrict__ Vb,
                                             u16* __restrict__ Vt) {
  __shared__ u16 tile[64*68];              // pad 68: 8B-aligned rows, low conflicts
  const int bh = blockIdx.y, s0 = blockIdx.x * 64, t = threadIdx.x;
#pragma unroll
  for (int i = 0; i < 2; ++i) {
    int chunk = i*256 + t;                 // [0,512)
    int sl = chunk >> 3, c8 = chunk & 7;
    u16x8 v = *reinterpret_cast<const u16x8*>(Vb + ((size_t)bh*S_ + s0 + sl)*HD_ + c8*8);
    u16x4 lo = __builtin_shufflevector(v, v, 0, 1, 2, 3);
    u16x4 hi = __builtin_shufflevector(v, v, 4, 5, 6, 7);
    *reinterpret_cast<u16x4*>(&tile[sl*68 + c8*8])     = lo;
    *reinterpret_cast<u16x4*>(&tile[sl*68 + c8*8 + 4]) = hi;
  }
  __syncthreads();
#pragma unroll
  for (int i = 0; i < 2; ++i) {
    int chunk = i*256 + t;
    int hd = chunk >> 3, sb = chunk & 7;
    u16x8 o;
#pragma unroll
    for (int k = 0; k < 8; ++k) {
      int p   = sb*8 + k;
      int key = (p & ~15) | (p & 3) | ((p & 4) << 1) | ((p & 8) >> 1);
      o[k] = tile[key*68 + hd];
    }
    *reinterpret_cast<u16x8*>(Vt + ((size_t)bh*HD_ + hd)*S_ + s0 + sb*8) = o;
  }
}

// ---------------- flash attention: 4 waves x 32 q-rows, 32x32x16 MFMA ----------
// KT=128 staging (barriers halved vs KT=64); inner loop = 2 half-tiles of 64
// keys with the round-5-verified math. Swapped QK^T (mfma(K,Q)); P in registers
// (pk2 -> native A-frag order); Vt key-permuted so PV B is a plain swizzled
// ds_read_b128. K LDS rows 128B: 3-bit XOR swizzle (inherent 4-way residue);
// V LDS rows 256B: 4-bit XOR swizzle (2-way, free). Fixed-max softmax.
#define QBW 32
#define NWV 4
#define QTT (QBW*NWV)    // 128 q-rows per block
#define KTL 128
#define NTL (S_/KTL)     // 16 kv tiles

__global__ __launch_bounds__(256) void k_attn(const u16* __restrict__ Q,
                                              const u16* __restrict__ K,
                                              const u16* __restrict__ Vt,
                                              float* __restrict__ out) {
  __shared__ alignas(16) u16 Ks[2][KTL*HD_];   // [key][hd], 16KB, col^=(row&7)
  __shared__ alignas(16) u16 Vs[2][HD_*KTL];   // [hd][key-perm], 16KB, col^=(row&15)
  __shared__ float lsums[NWV][QBW];
  const int t = threadIdx.x, l = t & 63, w = t >> 6;
  const int q32 = l & 31, hi = l >> 5;

  const int bid = blockIdx.x;
  const int work = (bid & 7) * 64 + (bid >> 3);   // XCD-chunked (512 % 8 == 0)
  const int bh = work >> 4;                       // 4 bh per XCD
  const int q0 = (work & 15) * QTT;

  const u16* Qg = Q  + ((size_t)bh*S_ + q0 + w*QBW)*HD_;
  const u16* Kg = K  + (size_t)bh*S_*HD_;
  const u16* Vg = Vt + (size_t)bh*HD_*S_;

  // Q B-frags (col=qrow=q32, k = kt*16 + hi*8 + i), loaded once from global
  bf16x8 qf[4];
#pragma unroll
  for (int kt = 0; kt < 4; ++kt)
    qf[kt] = *reinterpret_cast<const bf16x8*>(Qg + (size_t)q32*HD_ + kt*16 + hi*8);

  f32x16 O0 = {}, O1 = {};
  float lsum = 0.f;

  // staging pointers: thread t owns granules {t+256*i}; source pre-swizzled
  // (rule #21): K col ^= row&7 (8 granules/row), V col ^= row&15 (16/row).
  const u16* ksrc[4]; const u16* vsrc[4];
#pragma unroll
  for (int i = 0; i < 4; ++i) {
    int g  = t + 256*i;
    int kr = g >> 3,  kc = (g & 7)  ^ (kr & 7);
    ksrc[i] = Kg + (size_t)kr*HD_ + kc*8;
    int vr = g >> 4,  vc = (g & 15) ^ (vr & 15);
    vsrc[i] = Vg + (size_t)vr*S_ + vc*8;
  }

  // prologue: stage tile 0 into buf 0
#pragma unroll
  for (int i = 0; i < 4; ++i) {
    gload_lds16(ksrc[i], &Ks[0][(t + 256*i)*8]);
    gload_lds16(vsrc[i], &Vs[0][(t + 256*i)*8]);
  }
  __syncthreads();

  int cur = 0;
  for (int tile = 0; tile < NTL; ++tile) {
    if (tile + 1 < NTL) {
#pragma unroll
      for (int i = 0; i < 4; ++i) {
        gload_lds16(ksrc[i] + (size_t)(tile+1)*KTL*HD_, &Ks[cur^1][(t + 256*i)*8]);
        gload_lds16(vsrc[i] + (tile+1)*KTL,             &Vs[cur^1][(t + 256*i)*8]);
      }
    }

#pragma unroll
    for (int half = 0; half < 2; ++half) {
      // QK^T swapped: d[key][qrow]; A = K rows (key=half*64+kb*32+q32), B = Q
      f32x16 d0 = {}, d1 = {};
      __builtin_amdgcn_s_setprio(1);
#pragma unroll
      for (int kt = 0; kt < 4; ++kt) {
        const int gsw = ((kt*2 + hi) ^ (q32 & 7)) * 8;
        bf16x8 k0 = *reinterpret_cast<const bf16x8*>(&Ks[cur][(half*64 + q32)*HD_ + gsw]);
        d0 = __builtin_amdgcn_mfma_f32_32x32x16_bf16(k0, qf[kt], d0, 0, 0, 0);
        bf16x8 k1 = *reinterpret_cast<const bf16x8*>(&Ks[cur][(half*64 + 32 + q32)*HD_ + gsw]);
        d1 = __builtin_amdgcn_mfma_f32_32x32x16_bf16(k1, qf[kt], d1, 0, 0, 0);
      }
      __builtin_amdgcn_s_setprio(0);

      // softmax (fixed max, log2 domain) + pack to PV A-frags in native order.
      // chunk c element (hi,i) <-> key half*64 + c*16 + [(i&3)+8*(i>>2)+4*hi],
      // matching Vt's permuted key axis.
      unsigned pw[4][4];
#pragma unroll
      for (int c = 0; c < 4; ++c) {
        float e[8];
#pragma unroll
        for (int i = 0; i < 8; ++i) {
          float sv = (c < 2) ? d0[(c & 1)*8 + i] : d1[(c & 1)*8 + i];
          e[i] = exp2f(sv);
          lsum += e[i];
        }
#pragma unroll
        for (int j = 0; j < 4; ++j) pw[c][j] = pk2(e[2*j], e[2*j+1]);
      }

      // PV: O[qrow][hd] += P * V; B from Vs rows (hd), keys pre-permuted
      __builtin_amdgcn_s_setprio(1);
#pragma unroll
      for (int c = 0; c < 4; ++c) {
        u32x4v pv_ = {pw[c][0], pw[c][1], pw[c][2], pw[c][3]};
        bf16x8 pa = __builtin_bit_cast(bf16x8, pv_);
        const int gv = ((half*8 + c*2 + hi) ^ (q32 & 15)) * 8;
        bf16x8 v0 = *reinterpret_cast<const bf16x8*>(&Vs[cur][q32*KTL + gv]);
        O0 = __builtin_amdgcn_mfma_f32_32x32x16_bf16(pa, v0, O0, 0, 0, 0);
        bf16x8 v1 = *reinterpret_cast<const bf16x8*>(&Vs[cur][(32 + q32)*KTL + gv]);
        O1 = __builtin_amdgcn_mfma_f32_32x32x16_bf16(pa, v1, O1, 0, 0, 0);
      }
      __builtin_amdgcn_s_setprio(0);
    }

    __syncthreads();   // drains vmcnt (next buf staged) before swap
    cur ^= 1;
  }

  // full row sum: this lane's 64 keys/tile + partner's 64
  lsum += __shfl_xor(lsum, 32);
  if (l < 32) lsums[w][l] = lsum;    // lsums[w][qrow]; same-wave ds ordering

  // epilogue: O layout col=q32 (hd), row(reg r) = (r&3)+8*(r>>2)+4*hi (qrow)
  const int b = bh >> 4, h = bh & 15;
#pragma unroll
  for (int r = 0; r < 16; ++r) {
    int qrow = (r & 3) + 8*(r >> 2) + 4*hi;
    float inv = 1.f / lsums[w][qrow];
    size_t o = (size_t)(b*S_ + q0 + w*QBW + qrow)*D_ + h*HD_;
    out[o + q32]      = O0[r] * inv;
    out[o + 32 + q32] = O1[r] * inv;
  }
}

// ---------------- launch ----------------
extern "C" void kernel_launch(void* const* d_in, const int* in_sizes, int n_in,
                              void* d_out, int out_size, void* d_ws, size_t ws_size,
                              hipStream_t stream) {
  const float* hs = (const float*)d_in[0];
  const float* Wq = (const float*)d_in[1];
  const float* bq = (const float*)d_in[2];
  const float* Wk = (const float*)d_in[3];
  const float* bk = (const float*)d_in[4];
  const float* Wv = (const float*)d_in[5];
  const float* bv = (const float*)d_in[6];
  float* out = (float*)d_out;

  // ws layout (~48.8 MB total)
  char* ws = (char*)d_ws;
  u16*   Xb   = (u16*)  (ws);                 //  8.0 MB  X bf16 (4096x1024)
  u16*   Wb   = (u16*)  (ws + 8388608);       //  6.0 MB  W stacked bf16 (3072x1024)
  u16*   Qb   = (u16*)  (ws + 14680064);      //  8.0 MB  Q bf16 (B,H,S,HD), pre-scaled
  u16*   Kb   = (u16*)  (ws + 23068672);      //  8.0 MB  K bf16 (B,H,S,HD)
  u16*   Vb   = (u16*)  (ws + 31457280);      //  8.0 MB  V bf16 (B,H,S,HD)
  u16*   Vtb  = (u16*)  (ws + 39845888);      //  8.0 MB  V^T bf16 (B,H,HD,S), key-permuted
  float* sinT = (float*)(ws + 48234496);      //  0.25 MB
  float* cosT = (float*)(ws + 48496640);      //  0.25 MB

  k_prep<<<(M_*D_/4 + 3*(D_*D_/4)) / 256, 256, 0, stream>>>(hs, Wq, Wk, Wv, Xb, Wb);
  k_tables<<<256, 256, 0, stream>>>(sinT, cosT);
  k_gemm<<<dim3(N3/BN, M_/BM), 256, 0, stream>>>(Xb, Wb, bq, bk, bv, sinT, cosT, Qb, Kb, Vb);
  k_vt2<<<dim3(S_/64, B_*H_), 256, 0, stream>>>(Vb, Vtb);
  k_attn<<<512, 256, 0, stream>>>(Qb, Kb, Vtb, out);
}

// Round 8
// 183.906 us; speedup vs baseline: 1.1239x; 1.1192x over previous
//
#include <hip/hip_runtime.h>
#include <hip/hip_bf16.h>
#include <math.h>

// Problem constants (B=2, S=2048, D=1024, H=16, HD=64)
#define B_  2
#define S_  2048
#define D_  1024
#define H_  16
#define HD_ 64
#define M_  (B_*S_)     // 4096 rows (b,s)
#define N3  (3*D_)      // 3072 stacked Q|K|V projection cols
#define K_  D_          // 1024 contraction
#define LOG2E 1.44269504088896340736f

typedef unsigned short u16;
typedef __bf16 bf16x8 __attribute__((ext_vector_type(8)));
typedef float  f32x4  __attribute__((ext_vector_type(4)));
typedef float  f32x16 __attribute__((ext_vector_type(16)));
typedef unsigned short u16x4 __attribute__((ext_vector_type(4)));
typedef unsigned short u16x8 __attribute__((ext_vector_type(8)));
typedef unsigned int   u32x4v __attribute__((ext_vector_type(4)));

typedef const __attribute__((address_space(1))) unsigned int gu32;
typedef __attribute__((address_space(3)))       unsigned int lu32;

// async global->LDS, 16B per lane. LDS dest must be wave-uniform base + lane*16.
__device__ __forceinline__ void gload_lds16(const void* g, void* l) {
  __builtin_amdgcn_global_load_lds((gu32*)g, (lu32*)l, 16, 0, 0);
}

// round-to-nearest-even f32 -> bf16
__device__ __forceinline__ u16 f2bf(float f) {
  unsigned u = __builtin_bit_cast(unsigned, f);
  u += 0x7fffu + ((u >> 16) & 1u);
  return (u16)(u >> 16);
}

// pack 2 f32 -> 2 bf16 in one u32 (RNE), single instruction
__device__ __forceinline__ unsigned pk2(float lo, float hi) {
  unsigned d;
  asm("v_cvt_pk_bf16_f32 %0, %1, %2" : "=v"(d) : "v"(lo), "v"(hi));
  return d;
}

// ---------------- prep: f32->bf16 conversions + RoPE tables, one launch --------
// blocks [0, 7168): convert hs|Wq|Wk|Wv to bf16. blocks [7168, 7424): tables.
#define NPREP ((M_*D_/4 + 3*(D_*D_/4)) / 256)     // 7168
__global__ void k_prep(const float* __restrict__ hs, const float* __restrict__ Wq,
                       const float* __restrict__ Wk, const float* __restrict__ Wv,
                       u16* __restrict__ Xb, u16* __restrict__ Wb,
                       float* __restrict__ sinT, float* __restrict__ cosT) {
  const int NX = M_*D_/4, NW = D_*D_/4, NTOT = NX + 3*NW;
  int i = blockIdx.x * blockDim.x + threadIdx.x;
  if (i < NTOT) {
    const float4* src; u16* dst; int off;
    if (i < NX)            { src = (const float4*)hs; dst = Xb;           off = i; }
    else if (i < NX+NW)    { src = (const float4*)Wq; dst = Wb;           off = i-NX; }
    else if (i < NX+2*NW)  { src = (const float4*)Wk; dst = Wb + D_*D_;   off = i-NX-NW; }
    else                   { src = (const float4*)Wv; dst = Wb + 2*D_*D_; off = i-NX-2*NW; }
    float4 v = src[off];
    ushort4 o; o.x = f2bf(v.x); o.y = f2bf(v.y); o.z = f2bf(v.z); o.w = f2bf(v.w);
    reinterpret_cast<ushort4*>(dst)[off] = o;
  } else {
    int gid = i - NTOT;                   // [0, 2048*32)
    int s = gid >> 5, j = gid & 31;
    float invf = (float)exp(-(double)j * (log(10000.0) / 32.0));
    float angf = (float)s * invf;         // mimic f32 angle rounding of reference
    double ang = (double)angf;
    sinT[gid] = (float)sin(ang);
    cosT[gid] = (float)cos(ang);
  }
}

// ---------------- projection GEMM with fused bias+RoPE+transpose epilogue ------
#define BM 128
#define BN 128
#define BK 64

__global__ __launch_bounds__(256) void k_gemm(const u16* __restrict__ A,
                                              const u16* __restrict__ Bm,
                                              const float* __restrict__ bq,
                                              const float* __restrict__ bk,
                                              const float* __restrict__ bv,
                                              const float* __restrict__ sinT,
                                              const float* __restrict__ cosT,
                                              u16* __restrict__ Qo,
                                              u16* __restrict__ Ko,
                                              u16* __restrict__ Vt) {
  __shared__ alignas(16) u16 As[BM*BK];
  __shared__ alignas(16) u16 Bs[BN*BK];
  const int t = threadIdx.x;
  const int l = t & 63, w = t >> 6;
  const int wr = w >> 1, wc = w & 1;
  const int lr = l & 15, lg = l >> 4;

  // XCD-chunked block swizzle (768 blocks = 8 XCDs x 96, bijective)
  const int lin = blockIdx.y * (N3/BN) + blockIdx.x;
  const int wk  = (lin & 7) * 96 + (lin >> 3);
  const int m0 = (wk / (N3/BN)) * BM, n0 = (wk % (N3/BN)) * BN;

  f32x4 acc[4][4] = {};

  for (int k0 = 0; k0 < K_; k0 += BK) {
#pragma unroll
    for (int i = 0; i < 4; ++i) {          // A tile: 16KB, 4 x (256 lanes x 16B)
      int chunk = i*256 + t;
      int row = chunk >> 3, kc = chunk & 7;
      gload_lds16(A + (size_t)(m0+row)*K_ + k0 + kc*8, &As[chunk*8]);
    }
#pragma unroll
    for (int i = 0; i < 4; ++i) {          // B tile
      int chunk = i*256 + t;
      int row = chunk >> 3, kc = chunk & 7;
      gload_lds16(Bm + (size_t)(n0+row)*K_ + k0 + kc*8, &Bs[chunk*8]);
    }
    __syncthreads();
#pragma unroll
    for (int ks = 0; ks < 2; ++ks) {
      bf16x8 a[4], b[4];
#pragma unroll
      for (int m = 0; m < 4; ++m)
        a[m] = *reinterpret_cast<const bf16x8*>(&As[(wr*64 + m*16 + lr)*BK + ks*32 + lg*8]);
#pragma unroll
      for (int n = 0; n < 4; ++n)
        b[n] = *reinterpret_cast<const bf16x8*>(&Bs[(wc*64 + n*16 + lr)*BK + ks*32 + lg*8]);
#pragma unroll
      for (int m = 0; m < 4; ++m)
#pragma unroll
        for (int n = 0; n < 4; ++n)
          acc[m][n] = __builtin_amdgcn_mfma_f32_16x16x32_bf16(a[m], b[n], acc[m][n], 0, 0, 0);
    }
    __syncthreads();
  }

  // ---- fused epilogue ----  C/D layout: col = lane&15, row = (lane>>4)*4 + reg
  const int cw0  = n0 + wc*64;             // wave col base (64-aligned)
  const int proj = cw0 >> 10;              // 0=Q 1=K 2=V (wave-uniform)
  const int h    = (cw0 & (D_-1)) >> 6;
  const int b    = m0 >> 11;               // BM=128 divides S=2048
  const int sb_  = (m0 & (S_-1)) + wr*64;

  if (proj < 2) {
    const float* bias = proj ? bk : bq;
    u16* dst = proj ? Ko : Qo;
    // Q pre-scaled by 0.125*log2(e): folds softmax scale AND exp->exp2
    const float qs = proj ? 1.0f : 0.125f * LOG2E;
    float b1[2], b2[2];
#pragma unroll
    for (int n = 0; n < 2; ++n) {
      b1[n] = bias[h*HD_ + n*16 + lr];
      b2[n] = bias[h*HD_ + n*16 + lr + 32];
    }
#pragma unroll
    for (int m = 0; m < 4; ++m)
#pragma unroll
      for (int r = 0; r < 4; ++r) {
        int s = sb_ + m*16 + lg*4 + r;
        size_t orow = ((size_t)(b*H_ + h)*S_ + s)*HD_;
#pragma unroll
        for (int n = 0; n < 2; ++n) {
          int j = n*16 + lr;
          float x1 = acc[m][n][r]   + b1[n];
          float x2 = acc[m][n+2][r] + b2[n];
          float c  = cosT[(s<<5) + j], sn = sinT[(s<<5) + j];
          dst[orow + j]      = f2bf((x1*c - x2*sn) * qs);
          dst[orow + j + 32] = f2bf((x1*sn + x2*c) * qs);
        }
      }
  } else {
    // V: write Vt (B,H,HD,S) directly, key axis permuted within each 16-block
    // (swap bits 2<->3 of s&15 <=> relabel lg -> lgp). 8B stores, r contiguous.
    float bb[4];
#pragma unroll
    for (int n = 0; n < 4; ++n) bb[n] = bv[h*HD_ + n*16 + lr];
    const int lgp = ((lg & 1) << 1) | (lg >> 1);
    const int pos0 = sb_ + lgp*4;          // + m*16
#pragma unroll
    for (int m = 0; m < 4; ++m)
#pragma unroll
      for (int n = 0; n < 4; ++n) {
        int hd = n*16 + lr;
        u16x4 o;
#pragma unroll
        for (int r = 0; r < 4; ++r) o[r] = f2bf(acc[m][n][r] + bb[n]);
        *reinterpret_cast<u16x4*>(Vt + ((size_t)(b*H_ + h)*HD_ + hd)*S_ + pos0 + m*16) = o;
      }
  }
}

// ---------------- flash attention: 4 waves x 32 q-rows, 32x32x16 MFMA ----------
// KT=128 staging; inner loop = 2 half-tiles of 64 keys. Swapped QK^T (mfma(K,Q));
// P in registers (pk2 -> native A-frag order); Vt key-permuted so PV B is a plain
// swizzled ds_read_b128. Raw v_exp_f32 (scores bounded), 4-way lsum partials.
#define QBW 32
#define NWV 4
#define QTT (QBW*NWV)    // 128 q-rows per block
#define KTL 128
#define NTL (S_/KTL)     // 16 kv tiles

__global__ __launch_bounds__(256) void k_attn(const u16* __restrict__ Q,
                                              const u16* __restrict__ K,
                                              const u16* __restrict__ Vt,
                                              float* __restrict__ out) {
  __shared__ alignas(16) u16 Ks[2][KTL*HD_];   // [key][hd], 16KB, col^=(row&7)
  __shared__ alignas(16) u16 Vs[2][HD_*KTL];   // [hd][key-perm], 16KB, col^=(row&15)
  __shared__ float lsums[NWV][QBW];
  const int t = threadIdx.x, l = t & 63, w = t >> 6;
  const int q32 = l & 31, hi = l >> 5;

  const int bid = blockIdx.x;
  const int work = (bid & 7) * 64 + (bid >> 3);   // XCD-chunked (512 % 8 == 0)
  const int bh = work >> 4;                       // 4 bh per XCD
  const int q0 = (work & 15) * QTT;

  const u16* Qg = Q  + ((size_t)bh*S_ + q0 + w*QBW)*HD_;
  const u16* Kg = K  + (size_t)bh*S_*HD_;
  const u16* Vg = Vt + (size_t)bh*HD_*S_;

  // Q B-frags (col=qrow=q32, k = kt*16 + hi*8 + i), loaded once from global
  bf16x8 qf[4];
#pragma unroll
  for (int kt = 0; kt < 4; ++kt)
    qf[kt] = *reinterpret_cast<const bf16x8*>(Qg + (size_t)q32*HD_ + kt*16 + hi*8);

  f32x16 O0 = {}, O1 = {};
  float lp0 = 0.f, lp1 = 0.f, lp2 = 0.f, lp3 = 0.f;

  // staging pointers: thread t owns granules {t+256*i}; source pre-swizzled
  // (rule #21): K col ^= row&7 (8 granules/row), V col ^= row&15 (16/row).
  const u16* ksrc[4]; const u16* vsrc[4];
#pragma unroll
  for (int i = 0; i < 4; ++i) {
    int g  = t + 256*i;
    int kr = g >> 3,  kc = (g & 7)  ^ (kr & 7);
    ksrc[i] = Kg + (size_t)kr*HD_ + kc*8;
    int vr = g >> 4,  vc = (g & 15) ^ (vr & 15);
    vsrc[i] = Vg + (size_t)vr*S_ + vc*8;
  }

  // prologue: stage tile 0 into buf 0
#pragma unroll
  for (int i = 0; i < 4; ++i) {
    gload_lds16(ksrc[i], &Ks[0][(t + 256*i)*8]);
    gload_lds16(vsrc[i], &Vs[0][(t + 256*i)*8]);
  }
  __syncthreads();

  int cur = 0;
  for (int tile = 0; tile < NTL; ++tile) {
    if (tile + 1 < NTL) {
#pragma unroll
      for (int i = 0; i < 4; ++i) {
        gload_lds16(ksrc[i] + (size_t)(tile+1)*KTL*HD_, &Ks[cur^1][(t + 256*i)*8]);
        gload_lds16(vsrc[i] + (tile+1)*KTL,             &Vs[cur^1][(t + 256*i)*8]);
      }
    }

#pragma unroll
    for (int half = 0; half < 2; ++half) {
      // QK^T swapped: d[key][qrow]; A = K rows (key=half*64+kb*32+q32), B = Q
      f32x16 d0 = {}, d1 = {};
      __builtin_amdgcn_s_setprio(1);
#pragma unroll
      for (int kt = 0; kt < 4; ++kt) {
        const int gsw = ((kt*2 + hi) ^ (q32 & 7)) * 8;
        bf16x8 k0 = *reinterpret_cast<const bf16x8*>(&Ks[cur][(half*64 + q32)*HD_ + gsw]);
        d0 = __builtin_amdgcn_mfma_f32_32x32x16_bf16(k0, qf[kt], d0, 0, 0, 0);
        bf16x8 k1 = *reinterpret_cast<const bf16x8*>(&Ks[cur][(half*64 + 32 + q32)*HD_ + gsw]);
        d1 = __builtin_amdgcn_mfma_f32_32x32x16_bf16(k1, qf[kt], d1, 0, 0, 0);
      }
      __builtin_amdgcn_s_setprio(0);

      // softmax (fixed max, log2 domain): raw v_exp_f32 (bounded scores), then
      // pack to PV A-frags in native order. chunk c element (hi,i) <-> key
      // half*64 + c*16 + [(i&3)+8*(i>>2)+4*hi], matching Vt's permuted key axis.
      unsigned pw[4][4];
#pragma unroll
      for (int c = 0; c < 4; ++c) {
        float e[8];
#pragma unroll
        for (int i = 0; i < 8; ++i) {
          float sv = (c < 2) ? d0[(c & 1)*8 + i] : d1[(c & 1)*8 + i];
          e[i] = __builtin_amdgcn_exp2f(sv);
        }
        lp0 += e[0] + e[4];
        lp1 += e[1] + e[5];
        lp2 += e[2] + e[6];
        lp3 += e[3] + e[7];
#pragma unroll
        for (int j = 0; j < 4; ++j) pw[c][j] = pk2(e[2*j], e[2*j+1]);
      }

      // PV: O[qrow][hd] += P * V; B from Vs rows (hd), keys pre-permuted
      __builtin_amdgcn_s_setprio(1);
#pragma unroll
      for (int c = 0; c < 4; ++c) {
        u32x4v pv_ = {pw[c][0], pw[c][1], pw[c][2], pw[c][3]};
        bf16x8 pa = __builtin_bit_cast(bf16x8, pv_);
        const int gv = ((half*8 + c*2 + hi) ^ (q32 & 15)) * 8;
        bf16x8 v0 = *reinterpret_cast<const bf16x8*>(&Vs[cur][q32*KTL + gv]);
        O0 = __builtin_amdgcn_mfma_f32_32x32x16_bf16(pa, v0, O0, 0, 0, 0);
        bf16x8 v1 = *reinterpret_cast<const bf16x8*>(&Vs[cur][(32 + q32)*KTL + gv]);
        O1 = __builtin_amdgcn_mfma_f32_32x32x16_bf16(pa, v1, O1, 0, 0, 0);
      }
      __builtin_amdgcn_s_setprio(0);
    }

    __syncthreads();   // drains vmcnt (next buf staged) before swap
    cur ^= 1;
  }

  // full row sum: fold partials, then this lane's 64 keys + partner's 64
  float lsum = (lp0 + lp1) + (lp2 + lp3);
  lsum += __shfl_xor(lsum, 32);
  if (l < 32) lsums[w][l] = lsum;    // lsums[w][qrow]; same-wave ds ordering

  // epilogue: O layout col=q32 (hd), row(reg r) = (r&3)+8*(r>>2)+4*hi (qrow)
  const int b = bh >> 4, h = bh & 15;
#pragma unroll
  for (int r = 0; r < 16; ++r) {
    int qrow = (r & 3) + 8*(r >> 2) + 4*hi;
    float inv = 1.f / lsums[w][qrow];
    size_t o = (size_t)(b*S_ + q0 + w*QBW + qrow)*D_ + h*HD_;
    out[o + q32]      = O0[r] * inv;
    out[o + 32 + q32] = O1[r] * inv;
  }
}

// ---------------- launch ----------------
extern "C" void kernel_launch(void* const* d_in, const int* in_sizes, int n_in,
                              void* d_out, int out_size, void* d_ws, size_t ws_size,
                              hipStream_t stream) {
  const float* hs = (const float*)d_in[0];
  const float* Wq = (const float*)d_in[1];
  const float* bq = (const float*)d_in[2];
  const float* Wk = (const float*)d_in[3];
  const float* bk = (const float*)d_in[4];
  const float* Wv = (const float*)d_in[5];
  const float* bv = (const float*)d_in[6];
  float* out = (float*)d_out;

  // ws layout (~41 MB used)
  char* ws = (char*)d_ws;
  u16*   Xb   = (u16*)  (ws);                 //  8.0 MB  X bf16 (4096x1024)
  u16*   Wb   = (u16*)  (ws + 8388608);       //  6.0 MB  W stacked bf16 (3072x1024)
  u16*   Qb   = (u16*)  (ws + 14680064);      //  8.0 MB  Q bf16 (B,H,S,HD), pre-scaled
  u16*   Kb   = (u16*)  (ws + 23068672);      //  8.0 MB  K bf16 (B,H,S,HD)
  u16*   Vtb  = (u16*)  (ws + 31457280);      //  8.0 MB  V^T bf16 (B,H,HD,S), key-permuted
  float* sinT = (float*)(ws + 39845888);      //  0.25 MB
  float* cosT = (float*)(ws + 40108032);      //  0.25 MB

  k_prep<<<NPREP + 256, 256, 0, stream>>>(hs, Wq, Wk, Wv, Xb, Wb, sinT, cosT);
  k_gemm<<<dim3(N3/BN, M_/BM), 256, 0, stream>>>(Xb, Wb, bq, bk, bv, sinT, cosT, Qb, Kb, Vtb);
  k_attn<<<512, 256, 0, stream>>>(Qb, Kb, Vtb, out);
}

// Round 9
// 180.393 us; speedup vs baseline: 1.1457x; 1.0195x over previous
//
#include <hip/hip_runtime.h>
#include <hip/hip_bf16.h>
#include <math.h>

// Problem constants (B=2, S=2048, D=1024, H=16, HD=64)
#define B_  2
#define S_  2048
#define D_  1024
#define H_  16
#define HD_ 64
#define M_  (B_*S_)     // 4096 rows (b,s)
#define N3  (3*D_)      // 3072 stacked Q|K|V projection cols
#define K_  D_          // 1024 contraction
#define LOG2E 1.44269504088896340736f

typedef unsigned short u16;
typedef __bf16 bf16x8 __attribute__((ext_vector_type(8)));
typedef float  f32x4  __attribute__((ext_vector_type(4)));
typedef float  f32x16 __attribute__((ext_vector_type(16)));
typedef unsigned short u16x4 __attribute__((ext_vector_type(4)));
typedef unsigned short u16x8 __attribute__((ext_vector_type(8)));
typedef unsigned int   u32x4v __attribute__((ext_vector_type(4)));

typedef const __attribute__((address_space(1))) unsigned int gu32;
typedef __attribute__((address_space(3)))       unsigned int lu32;

// async global->LDS, 16B per lane. LDS dest must be wave-uniform base + lane*16.
__device__ __forceinline__ void gload_lds16(const void* g, void* l) {
  __builtin_amdgcn_global_load_lds((gu32*)g, (lu32*)l, 16, 0, 0);
}

// round-to-nearest-even f32 -> bf16
__device__ __forceinline__ u16 f2bf(float f) {
  unsigned u = __builtin_bit_cast(unsigned, f);
  u += 0x7fffu + ((u >> 16) & 1u);
  return (u16)(u >> 16);
}

// pack 2 f32 -> 2 bf16 in one u32 (RNE), single instruction
__device__ __forceinline__ unsigned pk2(float lo, float hi) {
  unsigned d;
  asm("v_cvt_pk_bf16_f32 %0, %1, %2" : "=v"(d) : "v"(lo), "v"(hi));
  return d;
}

// ---------------- prep: f32->bf16 conversions + RoPE tables, one launch --------
// blocks [0, 7168): convert hs|Wq|Wk|Wv to bf16. blocks [7168, 7424): tables.
#define NPREP ((M_*D_/4 + 3*(D_*D_/4)) / 256)     // 7168
__global__ void k_prep(const float* __restrict__ hs, const float* __restrict__ Wq,
                       const float* __restrict__ Wk, const float* __restrict__ Wv,
                       u16* __restrict__ Xb, u16* __restrict__ Wb,
                       float* __restrict__ sinT, float* __restrict__ cosT) {
  const int NX = M_*D_/4, NW = D_*D_/4, NTOT = NX + 3*NW;
  int i = blockIdx.x * blockDim.x + threadIdx.x;
  if (i < NTOT) {
    const float4* src; u16* dst; int off;
    if (i < NX)            { src = (const float4*)hs; dst = Xb;           off = i; }
    else if (i < NX+NW)    { src = (const float4*)Wq; dst = Wb;           off = i-NX; }
    else if (i < NX+2*NW)  { src = (const float4*)Wk; dst = Wb + D_*D_;   off = i-NX-NW; }
    else                   { src = (const float4*)Wv; dst = Wb + 2*D_*D_; off = i-NX-2*NW; }
    float4 v = src[off];
    ushort4 o; o.x = f2bf(v.x); o.y = f2bf(v.y); o.z = f2bf(v.z); o.w = f2bf(v.w);
    reinterpret_cast<ushort4*>(dst)[off] = o;
  } else {
    int gid = i - NTOT;                   // [0, 2048*32)
    int s = gid >> 5, j = gid & 31;
    float invf = (float)exp(-(double)j * (log(10000.0) / 32.0));
    float angf = (float)s * invf;         // mimic f32 angle rounding of reference
    double ang = (double)angf;
    sinT[gid] = (float)sin(ang);
    cosT[gid] = (float)cos(ang);
  }
}

// ---------------- projection GEMM: 2-phase double-buffered pipeline ------------
// Stage tile k+1 into buf^1 BEFORE computing tile k from buf (T3-minimum recipe);
// one barrier per K-step. Fused bias+RoPE+V-transpose epilogue unchanged.
#define BM 128
#define BN 128
#define BK 64

__global__ __launch_bounds__(256) void k_gemm(const u16* __restrict__ A,
                                              const u16* __restrict__ Bm,
                                              const float* __restrict__ bq,
                                              const float* __restrict__ bk,
                                              const float* __restrict__ bv,
                                              const float* __restrict__ sinT,
                                              const float* __restrict__ cosT,
                                              u16* __restrict__ Qo,
                                              u16* __restrict__ Ko,
                                              u16* __restrict__ Vt) {
  __shared__ alignas(16) u16 As[2][BM*BK];   // 2 x 16KB
  __shared__ alignas(16) u16 Bs[2][BN*BK];   // 2 x 16KB
  const int t = threadIdx.x;
  const int l = t & 63, w = t >> 6;
  const int wr = w >> 1, wc = w & 1;
  const int lr = l & 15, lg = l >> 4;

  // XCD-chunked block swizzle (768 blocks = 8 XCDs x 96, bijective)
  const int lin = blockIdx.y * (N3/BN) + blockIdx.x;
  const int wk  = (lin & 7) * 96 + (lin >> 3);
  const int m0 = (wk / (N3/BN)) * BM, n0 = (wk % (N3/BN)) * BN;

  // staging sources: thread t owns granules {t+256*i}; row = chunk>>3, kc = chunk&7
  const u16* asrc[4]; const u16* bsrc[4];
#pragma unroll
  for (int i = 0; i < 4; ++i) {
    int chunk = i*256 + t;
    int row = chunk >> 3, kc = chunk & 7;
    asrc[i] = A  + (size_t)(m0+row)*K_ + kc*8;
    bsrc[i] = Bm + (size_t)(n0+row)*K_ + kc*8;
  }

  f32x4 acc[4][4] = {};

  // prologue: stage k0=0 into buf 0
#pragma unroll
  for (int i = 0; i < 4; ++i) {
    int chunk = i*256 + t;
    gload_lds16(asrc[i], &As[0][chunk*8]);
    gload_lds16(bsrc[i], &Bs[0][chunk*8]);
  }
  __syncthreads();

  int cur = 0;
  for (int k0 = 0; k0 < K_; k0 += BK) {
    // issue next tile's stage first (latency hides under this tile's compute)
    if (k0 + BK < K_) {
#pragma unroll
      for (int i = 0; i < 4; ++i) {
        int chunk = i*256 + t;
        gload_lds16(asrc[i] + k0 + BK, &As[cur^1][chunk*8]);
        gload_lds16(bsrc[i] + k0 + BK, &Bs[cur^1][chunk*8]);
      }
    }
#pragma unroll
    for (int ks = 0; ks < 2; ++ks) {
      bf16x8 a[4], b[4];
#pragma unroll
      for (int m = 0; m < 4; ++m)
        a[m] = *reinterpret_cast<const bf16x8*>(&As[cur][(wr*64 + m*16 + lr)*BK + ks*32 + lg*8]);
#pragma unroll
      for (int n = 0; n < 4; ++n)
        b[n] = *reinterpret_cast<const bf16x8*>(&Bs[cur][(wc*64 + n*16 + lr)*BK + ks*32 + lg*8]);
#pragma unroll
      for (int m = 0; m < 4; ++m)
#pragma unroll
        for (int n = 0; n < 4; ++n)
          acc[m][n] = __builtin_amdgcn_mfma_f32_16x16x32_bf16(a[m], b[n], acc[m][n], 0, 0, 0);
    }
    __syncthreads();   // drains vmcnt (next buf staged) + all reads of cur done
    cur ^= 1;
  }

  // ---- fused epilogue ----  C/D layout: col = lane&15, row = (lane>>4)*4 + reg
  const int cw0  = n0 + wc*64;             // wave col base (64-aligned)
  const int proj = cw0 >> 10;              // 0=Q 1=K 2=V (wave-uniform)
  const int h    = (cw0 & (D_-1)) >> 6;
  const int b    = m0 >> 11;               // BM=128 divides S=2048
  const int sb_  = (m0 & (S_-1)) + wr*64;

  if (proj < 2) {
    const float* bias = proj ? bk : bq;
    u16* dst = proj ? Ko : Qo;
    // Q pre-scaled by 0.125*log2(e): folds softmax scale AND exp->exp2
    const float qs = proj ? 1.0f : 0.125f * LOG2E;
    float b1[2], b2[2];
#pragma unroll
    for (int n = 0; n < 2; ++n) {
      b1[n] = bias[h*HD_ + n*16 + lr];
      b2[n] = bias[h*HD_ + n*16 + lr + 32];
    }
#pragma unroll
    for (int m = 0; m < 4; ++m)
#pragma unroll
      for (int r = 0; r < 4; ++r) {
        int s = sb_ + m*16 + lg*4 + r;
        size_t orow = ((size_t)(b*H_ + h)*S_ + s)*HD_;
#pragma unroll
        for (int n = 0; n < 2; ++n) {
          int j = n*16 + lr;
          float x1 = acc[m][n][r]   + b1[n];
          float x2 = acc[m][n+2][r] + b2[n];
          float c  = cosT[(s<<5) + j], sn = sinT[(s<<5) + j];
          dst[orow + j]      = f2bf((x1*c - x2*sn) * qs);
          dst[orow + j + 32] = f2bf((x1*sn + x2*c) * qs);
        }
      }
  } else {
    // V: write Vt (B,H,HD,S) directly, key axis permuted within each 16-block
    // (swap bits 2<->3 of s&15 <=> relabel lg -> lgp). 8B stores, r contiguous.
    float bb[4];
#pragma unroll
    for (int n = 0; n < 4; ++n) bb[n] = bv[h*HD_ + n*16 + lr];
    const int lgp = ((lg & 1) << 1) | (lg >> 1);
    const int pos0 = sb_ + lgp*4;          // + m*16
#pragma unroll
    for (int m = 0; m < 4; ++m)
#pragma unroll
      for (int n = 0; n < 4; ++n) {
        int hd = n*16 + lr;
        u16x4 o;
#pragma unroll
        for (int r = 0; r < 4; ++r) o[r] = f2bf(acc[m][n][r] + bb[n]);
        *reinterpret_cast<u16x4*>(Vt + ((size_t)(b*H_ + h)*HD_ + hd)*S_ + pos0 + m*16) = o;
      }
  }
}

// ---------------- flash attention: 4 waves x 32 q-rows, 32x32x16 MFMA ----------
// KT=128 staging; inner loop = 2 half-tiles of 64 keys. Swapped QK^T (mfma(K,Q));
// P in registers (pk2 -> native A-frag order); Vt key-permuted so PV B is a plain
// swizzled ds_read_b128. Raw v_exp_f32 (scores bounded), 4-way lsum partials.
#define QBW 32
#define NWV 4
#define QTT (QBW*NWV)    // 128 q-rows per block
#define KTL 128
#define NTL (S_/KTL)     // 16 kv tiles

__global__ __launch_bounds__(256) void k_attn(const u16* __restrict__ Q,
                                              const u16* __restrict__ K,
                                              const u16* __restrict__ Vt,
                                              float* __restrict__ out) {
  __shared__ alignas(16) u16 Ks[2][KTL*HD_];   // [key][hd], 16KB, col^=(row&7)
  __shared__ alignas(16) u16 Vs[2][HD_*KTL];   // [hd][key-perm], 16KB, col^=(row&15)
  __shared__ float lsums[NWV][QBW];
  const int t = threadIdx.x, l = t & 63, w = t >> 6;
  const int q32 = l & 31, hi = l >> 5;

  const int bid = blockIdx.x;
  const int work = (bid & 7) * 64 + (bid >> 3);   // XCD-chunked (512 % 8 == 0)
  const int bh = work >> 4;                       // 4 bh per XCD
  const int q0 = (work & 15) * QTT;

  const u16* Qg = Q  + ((size_t)bh*S_ + q0 + w*QBW)*HD_;
  const u16* Kg = K  + (size_t)bh*S_*HD_;
  const u16* Vg = Vt + (size_t)bh*HD_*S_;

  // Q B-frags (col=qrow=q32, k = kt*16 + hi*8 + i), loaded once from global
  bf16x8 qf[4];
#pragma unroll
  for (int kt = 0; kt < 4; ++kt)
    qf[kt] = *reinterpret_cast<const bf16x8*>(Qg + (size_t)q32*HD_ + kt*16 + hi*8);

  f32x16 O0 = {}, O1 = {};
  float lp0 = 0.f, lp1 = 0.f, lp2 = 0.f, lp3 = 0.f;

  // staging pointers: thread t owns granules {t+256*i}; source pre-swizzled
  // (rule #21): K col ^= row&7 (8 granules/row), V col ^= row&15 (16/row).
  const u16* ksrc[4]; const u16* vsrc[4];
#pragma unroll
  for (int i = 0; i < 4; ++i) {
    int g  = t + 256*i;
    int kr = g >> 3,  kc = (g & 7)  ^ (kr & 7);
    ksrc[i] = Kg + (size_t)kr*HD_ + kc*8;
    int vr = g >> 4,  vc = (g & 15) ^ (vr & 15);
    vsrc[i] = Vg + (size_t)vr*S_ + vc*8;
  }

  // prologue: stage tile 0 into buf 0
#pragma unroll
  for (int i = 0; i < 4; ++i) {
    gload_lds16(ksrc[i], &Ks[0][(t + 256*i)*8]);
    gload_lds16(vsrc[i], &Vs[0][(t + 256*i)*8]);
  }
  __syncthreads();

  int cur = 0;
  for (int tile = 0; tile < NTL; ++tile) {
    if (tile + 1 < NTL) {
#pragma unroll
      for (int i = 0; i < 4; ++i) {
        gload_lds16(ksrc[i] + (size_t)(tile+1)*KTL*HD_, &Ks[cur^1][(t + 256*i)*8]);
        gload_lds16(vsrc[i] + (tile+1)*KTL,             &Vs[cur^1][(t + 256*i)*8]);
      }
    }

#pragma unroll
    for (int half = 0; half < 2; ++half) {
      // QK^T swapped: d[key][qrow]; A = K rows (key=half*64+kb*32+q32), B = Q
      f32x16 d0 = {}, d1 = {};
      __builtin_amdgcn_s_setprio(1);
#pragma unroll
      for (int kt = 0; kt < 4; ++kt) {
        const int gsw = ((kt*2 + hi) ^ (q32 & 7)) * 8;
        bf16x8 k0 = *reinterpret_cast<const bf16x8*>(&Ks[cur][(half*64 + q32)*HD_ + gsw]);
        d0 = __builtin_amdgcn_mfma_f32_32x32x16_bf16(k0, qf[kt], d0, 0, 0, 0);
        bf16x8 k1 = *reinterpret_cast<const bf16x8*>(&Ks[cur][(half*64 + 32 + q32)*HD_ + gsw]);
        d1 = __builtin_amdgcn_mfma_f32_32x32x16_bf16(k1, qf[kt], d1, 0, 0, 0);
      }
      __builtin_amdgcn_s_setprio(0);

      // softmax (fixed max, log2 domain): raw v_exp_f32 (bounded scores), then
      // pack to PV A-frags in native order. chunk c element (hi,i) <-> key
      // half*64 + c*16 + [(i&3)+8*(i>>2)+4*hi], matching Vt's permuted key axis.
      unsigned pw[4][4];
#pragma unroll
      for (int c = 0; c < 4; ++c) {
        float e[8];
#pragma unroll
        for (int i = 0; i < 8; ++i) {
          float sv = (c < 2) ? d0[(c & 1)*8 + i] : d1[(c & 1)*8 + i];
          e[i] = __builtin_amdgcn_exp2f(sv);
        }
        lp0 += e[0] + e[4];
        lp1 += e[1] + e[5];
        lp2 += e[2] + e[6];
        lp3 += e[3] + e[7];
#pragma unroll
        for (int j = 0; j < 4; ++j) pw[c][j] = pk2(e[2*j], e[2*j+1]);
      }

      // PV: O[qrow][hd] += P * V; B from Vs rows (hd), keys pre-permuted
      __builtin_amdgcn_s_setprio(1);
#pragma unroll
      for (int c = 0; c < 4; ++c) {
        u32x4v pv_ = {pw[c][0], pw[c][1], pw[c][2], pw[c][3]};
        bf16x8 pa = __builtin_bit_cast(bf16x8, pv_);
        const int gv = ((half*8 + c*2 + hi) ^ (q32 & 15)) * 8;
        bf16x8 v0 = *reinterpret_cast<const bf16x8*>(&Vs[cur][q32*KTL + gv]);
        O0 = __builtin_amdgcn_mfma_f32_32x32x16_bf16(pa, v0, O0, 0, 0, 0);
        bf16x8 v1 = *reinterpret_cast<const bf16x8*>(&Vs[cur][(32 + q32)*KTL + gv]);
        O1 = __builtin_amdgcn_mfma_f32_32x32x16_bf16(pa, v1, O1, 0, 0, 0);
      }
      __builtin_amdgcn_s_setprio(0);
    }

    __syncthreads();   // drains vmcnt (next buf staged) before swap
    cur ^= 1;
  }

  // full row sum: fold partials, then this lane's 64 keys + partner's 64
  float lsum = (lp0 + lp1) + (lp2 + lp3);
  lsum += __shfl_xor(lsum, 32);
  if (l < 32) lsums[w][l] = lsum;    // lsums[w][qrow]; same-wave ds ordering

  // epilogue: O layout col=q32 (hd), row(reg r) = (r&3)+8*(r>>2)+4*hi (qrow)
  const int b = bh >> 4, h = bh & 15;
#pragma unroll
  for (int r = 0; r < 16; ++r) {
    int qrow = (r & 3) + 8*(r >> 2) + 4*hi;
    float inv = 1.f / lsums[w][qrow];
    size_t o = (size_t)(b*S_ + q0 + w*QBW + qrow)*D_ + h*HD_;
    out[o + q32]      = O0[r] * inv;
    out[o + 32 + q32] = O1[r] * inv;
  }
}

// ---------------- launch ----------------
extern "C" void kernel_launch(void* const* d_in, const int* in_sizes, int n_in,
                              void* d_out, int out_size, void* d_ws, size_t ws_size,
                              hipStream_t stream) {
  const float* hs = (const float*)d_in[0];
  const float* Wq = (const float*)d_in[1];
  const float* bq = (const float*)d_in[2];
  const float* Wk = (const float*)d_in[3];
  const float* bk = (const float*)d_in[4];
  const float* Wv = (const float*)d_in[5];
  const float* bv = (const float*)d_in[6];
  float* out = (float*)d_out;

  // ws layout (~41 MB used)
  char* ws = (char*)d_ws;
  u16*   Xb   = (u16*)  (ws);                 //  8.0 MB  X bf16 (4096x1024)
  u16*   Wb   = (u16*)  (ws + 8388608);       //  6.0 MB  W stacked bf16 (3072x1024)
  u16*   Qb   = (u16*)  (ws + 14680064);      //  8.0 MB  Q bf16 (B,H,S,HD), pre-scaled
  u16*   Kb   = (u16*)  (ws + 23068672);      //  8.0 MB  K bf16 (B,H,S,HD)
  u16*   Vtb  = (u16*)  (ws + 31457280);      //  8.0 MB  V^T bf16 (B,H,HD,S), key-permuted
  float* sinT = (float*)(ws + 39845888);      //  0.25 MB
  float* cosT = (float*)(ws + 40108032);      //  0.25 MB

  k_prep<<<NPREP + 256, 256, 0, stream>>>(hs, Wq, Wk, Wv, Xb, Wb, sinT, cosT);
  k_gemm<<<dim3(N3/BN, M_/BM), 256, 0, stream>>>(Xb, Wb, bq, bk, bv, sinT, cosT, Qb, Kb, Vtb);
  k_attn<<<512, 256, 0, stream>>>(Qb, Kb, Vtb, out);
}

// Round 10
// 172.677 us; speedup vs baseline: 1.1969x; 1.0447x over previous
//
#include <hip/hip_runtime.h>
#include <hip/hip_bf16.h>
#include <math.h>

// Problem constants (B=2, S=2048, D=1024, H=16, HD=64)
#define B_  2
#define S_  2048
#define D_  1024
#define H_  16
#define HD_ 64
#define M_  (B_*S_)     // 4096 rows (b,s)
#define N3  (3*D_)      // 3072 stacked Q|K|V projection cols
#define K_  D_          // 1024 contraction
#define LOG2E 1.44269504088896340736f

typedef unsigned short u16;
typedef __bf16 bf16x8 __attribute__((ext_vector_type(8)));
typedef float  f32x4  __attribute__((ext_vector_type(4)));
typedef float  f32x16 __attribute__((ext_vector_type(16)));
typedef unsigned short u16x4 __attribute__((ext_vector_type(4)));
typedef unsigned short u16x8 __attribute__((ext_vector_type(8)));
typedef unsigned int   u32x4v __attribute__((ext_vector_type(4)));

typedef const __attribute__((address_space(1))) unsigned int gu32;
typedef __attribute__((address_space(3)))       unsigned int lu32;

// async global->LDS, 16B per lane. LDS dest must be wave-uniform base + lane*16.
__device__ __forceinline__ void gload_lds16(const void* g, void* l) {
  __builtin_amdgcn_global_load_lds((gu32*)g, (lu32*)l, 16, 0, 0);
}

// round-to-nearest-even f32 -> bf16
__device__ __forceinline__ u16 f2bf(float f) {
  unsigned u = __builtin_bit_cast(unsigned, f);
  u += 0x7fffu + ((u >> 16) & 1u);
  return (u16)(u >> 16);
}

// pack 2 f32 -> 2 bf16 in one u32 (RNE), single instruction
__device__ __forceinline__ unsigned pk2(float lo, float hi) {
  unsigned d;
  asm("v_cvt_pk_bf16_f32 %0, %1, %2" : "=v"(d) : "v"(lo), "v"(hi));
  return d;
}

// ---------------- prep: f32->bf16 conversions + RoPE tables, one launch --------
// blocks [0, 7168): convert hs|Wq|Wk|Wv to bf16. blocks [7168, 7424): tables.
#define NPREP ((M_*D_/4 + 3*(D_*D_/4)) / 256)     // 7168
__global__ void k_prep(const float* __restrict__ hs, const float* __restrict__ Wq,
                       const float* __restrict__ Wk, const float* __restrict__ Wv,
                       u16* __restrict__ Xb, u16* __restrict__ Wb,
                       float* __restrict__ sinT, float* __restrict__ cosT) {
  const int NX = M_*D_/4, NW = D_*D_/4, NTOT = NX + 3*NW;
  int i = blockIdx.x * blockDim.x + threadIdx.x;
  if (i < NTOT) {
    const float4* src; u16* dst; int off;
    if (i < NX)            { src = (const float4*)hs; dst = Xb;           off = i; }
    else if (i < NX+NW)    { src = (const float4*)Wq; dst = Wb;           off = i-NX; }
    else if (i < NX+2*NW)  { src = (const float4*)Wk; dst = Wb + D_*D_;   off = i-NX-NW; }
    else                   { src = (const float4*)Wv; dst = Wb + 2*D_*D_; off = i-NX-2*NW; }
    float4 v = src[off];
    ushort4 o; o.x = f2bf(v.x); o.y = f2bf(v.y); o.z = f2bf(v.z); o.w = f2bf(v.w);
    reinterpret_cast<ushort4*>(dst)[off] = o;
  } else {
    int gid = i - NTOT;                   // [0, 2048*32)
    int s = gid >> 5, j = gid & 31;
    float invf = (float)exp(-(double)j * (log(10000.0) / 32.0));
    float angf = (float)s * invf;         // mimic f32 angle rounding of reference
    double ang = (double)angf;
    sinT[gid] = (float)sin(ang);
    cosT[gid] = (float)cos(ang);
  }
}

// ---------------- projection GEMM: 2-phase dbuf + T2 XOR-swizzled LDS ----------
// As/Bs rows are 128B -> unswizzled fragment reads are 16-way bank conflicts
// (G4). Fix per rule #21: linear LDS dest, pre-swizzled GLOBAL source granule
// (kc ^ (row&7)), same XOR on the read granule. 2-phase: stage k+1 into buf^1
// before computing buf; one barrier per K-step.
#define BM 128
#define BN 128
#define BK 64

__global__ __launch_bounds__(256) void k_gemm(const u16* __restrict__ A,
                                              const u16* __restrict__ Bm,
                                              const float* __restrict__ bq,
                                              const float* __restrict__ bk,
                                              const float* __restrict__ bv,
                                              const float* __restrict__ sinT,
                                              const float* __restrict__ cosT,
                                              u16* __restrict__ Qo,
                                              u16* __restrict__ Ko,
                                              u16* __restrict__ Vt) {
  __shared__ alignas(16) u16 As[2][BM*BK];   // 2 x 16KB
  __shared__ alignas(16) u16 Bs[2][BN*BK];   // 2 x 16KB
  const int t = threadIdx.x;
  const int l = t & 63, w = t >> 6;
  const int wr = w >> 1, wc = w & 1;
  const int lr = l & 15, lg = l >> 4;

  // XCD-chunked block swizzle (768 blocks = 8 XCDs x 96, bijective)
  const int lin = blockIdx.y * (N3/BN) + blockIdx.x;
  const int wk  = (lin & 7) * 96 + (lin >> 3);
  const int m0 = (wk / (N3/BN)) * BM, n0 = (wk % (N3/BN)) * BN;

  // staging sources: thread t owns LDS granules {t+256*i}; global granule
  // pre-swizzled kc ^ (row&7) so the READ side is conflict-free (rule #21).
  const u16* asrc[4]; const u16* bsrc[4];
#pragma unroll
  for (int i = 0; i < 4; ++i) {
    int chunk = i*256 + t;
    int row = chunk >> 3, kc = (chunk & 7) ^ (row & 7);
    asrc[i] = A  + (size_t)(m0+row)*K_ + kc*8;
    bsrc[i] = Bm + (size_t)(n0+row)*K_ + kc*8;
  }

  f32x4 acc[4][4] = {};

  // prologue: stage k0=0 into buf 0
#pragma unroll
  for (int i = 0; i < 4; ++i) {
    int chunk = i*256 + t;
    gload_lds16(asrc[i], &As[0][chunk*8]);
    gload_lds16(bsrc[i], &Bs[0][chunk*8]);
  }
  __syncthreads();

  int cur = 0;
  for (int k0 = 0; k0 < K_; k0 += BK) {
    // issue next tile's stage first (latency hides under this tile's compute)
    if (k0 + BK < K_) {
#pragma unroll
      for (int i = 0; i < 4; ++i) {
        int chunk = i*256 + t;
        gload_lds16(asrc[i] + k0 + BK, &As[cur^1][chunk*8]);
        gload_lds16(bsrc[i] + k0 + BK, &Bs[cur^1][chunk*8]);
      }
    }
#pragma unroll
    for (int ks = 0; ks < 2; ++ks) {
      bf16x8 a[4], b[4];
#pragma unroll
      for (int m = 0; m < 4; ++m) {
        int row = wr*64 + m*16 + lr;
        int g   = (ks*4 + lg) ^ (row & 7);
        a[m] = *reinterpret_cast<const bf16x8*>(&As[cur][row*BK + g*8]);
      }
#pragma unroll
      for (int n = 0; n < 4; ++n) {
        int row = wc*64 + n*16 + lr;
        int g   = (ks*4 + lg) ^ (row & 7);
        b[n] = *reinterpret_cast<const bf16x8*>(&Bs[cur][row*BK + g*8]);
      }
#pragma unroll
      for (int m = 0; m < 4; ++m)
#pragma unroll
        for (int n = 0; n < 4; ++n)
          acc[m][n] = __builtin_amdgcn_mfma_f32_16x16x32_bf16(a[m], b[n], acc[m][n], 0, 0, 0);
    }
    __syncthreads();   // drains vmcnt (next buf staged) + all reads of cur done
    cur ^= 1;
  }

  // ---- fused epilogue ----  C/D layout: col = lane&15, row = (lane>>4)*4 + reg
  const int cw0  = n0 + wc*64;             // wave col base (64-aligned)
  const int proj = cw0 >> 10;              // 0=Q 1=K 2=V (wave-uniform)
  const int h    = (cw0 & (D_-1)) >> 6;
  const int b    = m0 >> 11;               // BM=128 divides S=2048
  const int sb_  = (m0 & (S_-1)) + wr*64;

  if (proj < 2) {
    const float* bias = proj ? bk : bq;
    u16* dst = proj ? Ko : Qo;
    // Q pre-scaled by 0.125*log2(e): folds softmax scale AND exp->exp2
    const float qs = proj ? 1.0f : 0.125f * LOG2E;
    float b1[2], b2[2];
#pragma unroll
    for (int n = 0; n < 2; ++n) {
      b1[n] = bias[h*HD_ + n*16 + lr];
      b2[n] = bias[h*HD_ + n*16 + lr + 32];
    }
#pragma unroll
    for (int m = 0; m < 4; ++m)
#pragma unroll
      for (int r = 0; r < 4; ++r) {
        int s = sb_ + m*16 + lg*4 + r;
        size_t orow = ((size_t)(b*H_ + h)*S_ + s)*HD_;
#pragma unroll
        for (int n = 0; n < 2; ++n) {
          int j = n*16 + lr;
          float x1 = acc[m][n][r]   + b1[n];
          float x2 = acc[m][n+2][r] + b2[n];
          float c  = cosT[(s<<5) + j], sn = sinT[(s<<5) + j];
          dst[orow + j]      = f2bf((x1*c - x2*sn) * qs);
          dst[orow + j + 32] = f2bf((x1*sn + x2*c) * qs);
        }
      }
  } else {
    // V: write Vt (B,H,HD,S) directly, key axis permuted within each 16-block
    // (swap bits 2<->3 of s&15 <=> relabel lg -> lgp). 8B stores, r contiguous.
    float bb[4];
#pragma unroll
    for (int n = 0; n < 4; ++n) bb[n] = bv[h*HD_ + n*16 + lr];
    const int lgp = ((lg & 1) << 1) | (lg >> 1);
    const int pos0 = sb_ + lgp*4;          // + m*16
#pragma unroll
    for (int m = 0; m < 4; ++m)
#pragma unroll
      for (int n = 0; n < 4; ++n) {
        int hd = n*16 + lr;
        u16x4 o;
#pragma unroll
        for (int r = 0; r < 4; ++r) o[r] = f2bf(acc[m][n][r] + bb[n]);
        *reinterpret_cast<u16x4*>(Vt + ((size_t)(b*H_ + h)*HD_ + hd)*S_ + pos0 + m*16) = o;
      }
  }
}

// ---------------- flash attention: 4 waves x 32 q-rows, 32x32x16 MFMA ----------
// KT=128 staging; inner loop = 2 half-tiles of 64 keys. Swapped QK^T (mfma(K,Q));
// P in registers (pk2 -> native A-frag order); Vt key-permuted so PV B is a plain
// swizzled ds_read_b128. Raw v_exp_f32 (scores bounded), 4-way lsum partials.
#define QBW 32
#define NWV 4
#define QTT (QBW*NWV)    // 128 q-rows per block
#define KTL 128
#define NTL (S_/KTL)     // 16 kv tiles

__global__ __launch_bounds__(256) void k_attn(const u16* __restrict__ Q,
                                              const u16* __restrict__ K,
                                              const u16* __restrict__ Vt,
                                              float* __restrict__ out) {
  __shared__ alignas(16) u16 Ks[2][KTL*HD_];   // [key][hd], 16KB, col^=(row&7)
  __shared__ alignas(16) u16 Vs[2][HD_*KTL];   // [hd][key-perm], 16KB, col^=(row&15)
  __shared__ float lsums[NWV][QBW];
  const int t = threadIdx.x, l = t & 63, w = t >> 6;
  const int q32 = l & 31, hi = l >> 5;

  const int bid = blockIdx.x;
  const int work = (bid & 7) * 64 + (bid >> 3);   // XCD-chunked (512 % 8 == 0)
  const int bh = work >> 4;                       // 4 bh per XCD
  const int q0 = (work & 15) * QTT;

  const u16* Qg = Q  + ((size_t)bh*S_ + q0 + w*QBW)*HD_;
  const u16* Kg = K  + (size_t)bh*S_*HD_;
  const u16* Vg = Vt + (size_t)bh*HD_*S_;

  // Q B-frags (col=qrow=q32, k = kt*16 + hi*8 + i), loaded once from global
  bf16x8 qf[4];
#pragma unroll
  for (int kt = 0; kt < 4; ++kt)
    qf[kt] = *reinterpret_cast<const bf16x8*>(Qg + (size_t)q32*HD_ + kt*16 + hi*8);

  f32x16 O0 = {}, O1 = {};
  float lp0 = 0.f, lp1 = 0.f, lp2 = 0.f, lp3 = 0.f;

  // staging pointers: thread t owns granules {t+256*i}; source pre-swizzled
  // (rule #21): K col ^= row&7 (8 granules/row), V col ^= row&15 (16/row).
  const u16* ksrc[4]; const u16* vsrc[4];
#pragma unroll
  for (int i = 0; i < 4; ++i) {
    int g  = t + 256*i;
    int kr = g >> 3,  kc = (g & 7)  ^ (kr & 7);
    ksrc[i] = Kg + (size_t)kr*HD_ + kc*8;
    int vr = g >> 4,  vc = (g & 15) ^ (vr & 15);
    vsrc[i] = Vg + (size_t)vr*S_ + vc*8;
  }

  // prologue: stage tile 0 into buf 0
#pragma unroll
  for (int i = 0; i < 4; ++i) {
    gload_lds16(ksrc[i], &Ks[0][(t + 256*i)*8]);
    gload_lds16(vsrc[i], &Vs[0][(t + 256*i)*8]);
  }
  __syncthreads();

  int cur = 0;
  for (int tile = 0; tile < NTL; ++tile) {
    if (tile + 1 < NTL) {
#pragma unroll
      for (int i = 0; i < 4; ++i) {
        gload_lds16(ksrc[i] + (size_t)(tile+1)*KTL*HD_, &Ks[cur^1][(t + 256*i)*8]);
        gload_lds16(vsrc[i] + (tile+1)*KTL,             &Vs[cur^1][(t + 256*i)*8]);
      }
    }

#pragma unroll
    for (int half = 0; half < 2; ++half) {
      // QK^T swapped: d[key][qrow]; A = K rows (key=half*64+kb*32+q32), B = Q
      f32x16 d0 = {}, d1 = {};
      __builtin_amdgcn_s_setprio(1);
#pragma unroll
      for (int kt = 0; kt < 4; ++kt) {
        const int gsw = ((kt*2 + hi) ^ (q32 & 7)) * 8;
        bf16x8 k0 = *reinterpret_cast<const bf16x8*>(&Ks[cur][(half*64 + q32)*HD_ + gsw]);
        d0 = __builtin_amdgcn_mfma_f32_32x32x16_bf16(k0, qf[kt], d0, 0, 0, 0);
        bf16x8 k1 = *reinterpret_cast<const bf16x8*>(&Ks[cur][(half*64 + 32 + q32)*HD_ + gsw]);
        d1 = __builtin_amdgcn_mfma_f32_32x32x16_bf16(k1, qf[kt], d1, 0, 0, 0);
      }
      __builtin_amdgcn_s_setprio(0);

      // softmax (fixed max, log2 domain): raw v_exp_f32 (bounded scores), then
      // pack to PV A-frags in native order. chunk c element (hi,i) <-> key
      // half*64 + c*16 + [(i&3)+8*(i>>2)+4*hi], matching Vt's permuted key axis.
      unsigned pw[4][4];
#pragma unroll
      for (int c = 0; c < 4; ++c) {
        float e[8];
#pragma unroll
        for (int i = 0; i < 8; ++i) {
          float sv = (c < 2) ? d0[(c & 1)*8 + i] : d1[(c & 1)*8 + i];
          e[i] = __builtin_amdgcn_exp2f(sv);
        }
        lp0 += e[0] + e[4];
        lp1 += e[1] + e[5];
        lp2 += e[2] + e[6];
        lp3 += e[3] + e[7];
#pragma unroll
        for (int j = 0; j < 4; ++j) pw[c][j] = pk2(e[2*j], e[2*j+1]);
      }

      // PV: O[qrow][hd] += P * V; B from Vs rows (hd), keys pre-permuted
      __builtin_amdgcn_s_setprio(1);
#pragma unroll
      for (int c = 0; c < 4; ++c) {
        u32x4v pv_ = {pw[c][0], pw[c][1], pw[c][2], pw[c][3]};
        bf16x8 pa = __builtin_bit_cast(bf16x8, pv_);
        const int gv = ((half*8 + c*2 + hi) ^ (q32 & 15)) * 8;
        bf16x8 v0 = *reinterpret_cast<const bf16x8*>(&Vs[cur][q32*KTL + gv]);
        O0 = __builtin_amdgcn_mfma_f32_32x32x16_bf16(pa, v0, O0, 0, 0, 0);
        bf16x8 v1 = *reinterpret_cast<const bf16x8*>(&Vs[cur][(32 + q32)*KTL + gv]);
        O1 = __builtin_amdgcn_mfma_f32_32x32x16_bf16(pa, v1, O1, 0, 0, 0);
      }
      __builtin_amdgcn_s_setprio(0);
    }

    __syncthreads();   // drains vmcnt (next buf staged) before swap
    cur ^= 1;
  }

  // full row sum: fold partials, then this lane's 64 keys + partner's 64
  float lsum = (lp0 + lp1) + (lp2 + lp3);
  lsum += __shfl_xor(lsum, 32);
  if (l < 32) lsums[w][l] = lsum;    // lsums[w][qrow]; same-wave ds ordering

  // epilogue: O layout col=q32 (hd), row(reg r) = (r&3)+8*(r>>2)+4*hi (qrow)
  const int b = bh >> 4, h = bh & 15;
#pragma unroll
  for (int r = 0; r < 16; ++r) {
    int qrow = (r & 3) + 8*(r >> 2) + 4*hi;
    float inv = 1.f / lsums[w][qrow];
    size_t o = (size_t)(b*S_ + q0 + w*QBW + qrow)*D_ + h*HD_;
    out[o + q32]      = O0[r] * inv;
    out[o + 32 + q32] = O1[r] * inv;
  }
}

// ---------------- launch ----------------
extern "C" void kernel_launch(void* const* d_in, const int* in_sizes, int n_in,
                              void* d_out, int out_size, void* d_ws, size_t ws_size,
                              hipStream_t stream) {
  const float* hs = (const float*)d_in[0];
  const float* Wq = (const float*)d_in[1];
  const float* bq = (const float*)d_in[2];
  const float* Wk = (const float*)d_in[3];
  const float* bk = (const float*)d_in[4];
  const float* Wv = (const float*)d_in[5];
  const float* bv = (const float*)d_in[6];
  float* out = (float*)d_out;

  // ws layout (~41 MB used)
  char* ws = (char*)d_ws;
  u16*   Xb   = (u16*)  (ws);                 //  8.0 MB  X bf16 (4096x1024)
  u16*   Wb   = (u16*)  (ws + 8388608);       //  6.0 MB  W stacked bf16 (3072x1024)
  u16*   Qb   = (u16*)  (ws + 14680064);      //  8.0 MB  Q bf16 (B,H,S,HD), pre-scaled
  u16*   Kb   = (u16*)  (ws + 23068672);      //  8.0 MB  K bf16 (B,H,S,HD)
  u16*   Vtb  = (u16*)  (ws + 31457280);      //  8.0 MB  V^T bf16 (B,H,HD,S), key-permuted
  float* sinT = (float*)(ws + 39845888);      //  0.25 MB
  float* cosT = (float*)(ws + 40108032);      //  0.25 MB

  k_prep<<<NPREP + 256, 256, 0, stream>>>(hs, Wq, Wk, Wv, Xb, Wb, sinT, cosT);
  k_gemm<<<dim3(N3/BN, M_/BM), 256, 0, stream>>>(Xb, Wb, bq, bk, bv, sinT, cosT, Qb, Kb, Vtb);
  k_attn<<<512, 256, 0, stream>>>(Qb, Kb, Vtb, out);
}